// Round 6
// baseline (2399.201 us; speedup 1.0000x reference)
//
#include <hip/hip_runtime.h>

typedef unsigned short u16;
typedef unsigned int   u32;
typedef short short8 __attribute__((ext_vector_type(8)));
typedef float f32x4  __attribute__((ext_vector_type(4)));

__device__ __forceinline__ u16 f2bf(float f){
  u32 u = __float_as_uint(f);
  u32 r = (u + 0x7fffu + ((u >> 16) & 1u)) >> 16;
  return (u16)r;
}
__device__ __forceinline__ float lrn_one(float v, float pv){
  float avg = 0.5f*(v*v + pv*pv);
  float d = 1.0f + 2e-5f*avg;
  return v * exp2f(-0.75f * log2f(d));   // d >= 1, safe
}

// ---------------- K0a: prepack w5 fp32 [1024][64][16][16] -> bf16 fragment order
// Wpk5[ocb(8)][chunk(32)][kx(16)][quad(4)][oc128(128)][j(8)]
__global__ __launch_bounds__(256) void k0w5(const float* __restrict__ w5, u16* __restrict__ wpk){
  int idx = blockIdx.x*256 + threadIdx.x;            // 16,777,216
  int j     =  idx        & 7;
  int oc128 = (idx >> 3)  & 127;
  int quad  = (idx >> 10) & 3;
  int kx    = (idx >> 12) & 15;
  int chunk = (idx >> 16) & 31;
  int ocb   =  idx >> 21;
  int oc = ocb*128 + oc128;
  int ic = chunk*2 + (quad>>1);
  int ky = (quad&1)*8 + j;
  wpk[idx] = f2bf(w5[((oc*64 + ic)*16 + ky)*16 + kx]);
}

// ---------------- K0b: prepack w6 fp32[1024][1024] -> bf16
__global__ __launch_bounds__(256) void k0w6(const float* __restrict__ w6, u16* __restrict__ wpk){
  int idx = blockIdx.x*256 + threadIdx.x;            // 1,048,576
  wpk[idx] = f2bf(w6[idx]);
}

// ---------------- K0c: zero the k8 accumulation buffer (18432 f32)
__global__ __launch_bounds__(256) void k0z(float* __restrict__ accum){
  int idx = blockIdx.x*256 + threadIdx.x;
  if (idx < 18432) accum[idx] = 0.f;
}

// ---------------- K1: conv 7x7, 1->64, SAME pad 3, relu
__global__ __launch_bounds__(256) void k1_conv7x7(const float* __restrict__ x, const float* __restrict__ w1,
                                                  const float* __restrict__ b1, float* __restrict__ out){
  int idx = blockIdx.x*256 + threadIdx.x;            // 2,097,152
  int ox = idx & 127, oy = (idx>>7)&127, oc = (idx>>14)&63, n = idx>>20;
  float acc = b1[oc];
  const float* wb = w1 + oc*49;
  const float* xb = x + n*16384;
  #pragma unroll
  for (int ky=0;ky<7;++ky){
    int y = oy + ky - 3;
    if ((unsigned)y < 128u){
      #pragma unroll
      for (int kx=0;kx<7;++kx){
        int xx = ox + kx - 3;
        if ((unsigned)xx < 128u)
          acc += wb[ky*7+kx] * xb[y*128+xx];
      }
    }
  }
  out[idx] = acc > 0.f ? acc : 0.f;
}

// ---------------- K2 v2: conv 5x5, 64->64, SAME pad 2, relu. 1x4 px per thread.
// grid 2048 = [colg 2][rowg 8][oc 64][n 2]; block tile 16 rows x 64 cols.
__global__ __launch_bounds__(256) void k2_conv5x5(const float* __restrict__ in, const float* __restrict__ w2,
                                                  const float* __restrict__ b2, float* __restrict__ out){
  __shared__ __align__(16) float t[1360];            // 20 rows x 68 cols
  __shared__ float wl[25];
  int bid = blockIdx.x;
  int colg = bid & 1; int t1 = bid >> 1;
  int rowg = t1 & 7;  int t2 = t1 >> 3;
  int oc = t2 & 63;   int n = t2 >> 6;
  int tid = threadIdx.x;
  int oy0 = rowg*16, ox0 = colg*64;
  int r = tid >> 4, c0 = (tid & 15)*4;
  float acc[4] = {0.f,0.f,0.f,0.f};
  for (int ic=0; ic<64; ++ic){
    __syncthreads();
    for (int u=tid; u<1360; u+=256){
      int rr = u/68, cc = u - rr*68;
      int gy = oy0+rr-2, gx = ox0+cc-2;
      t[u] = ((unsigned)gy<128u && (unsigned)gx<128u) ? in[((n*64+ic)*128+gy)*128+gx] : 0.f;
    }
    if (tid < 25) wl[tid] = w2[(oc*64+ic)*25 + tid];
    __syncthreads();
    #pragma unroll
    for (int ky=0;ky<5;++ky){
      float4 a = *(const float4*)&t[(r+ky)*68 + c0];
      float4 b = *(const float4*)&t[(r+ky)*68 + c0 + 4];
      float f[8] = {a.x,a.y,a.z,a.w,b.x,b.y,b.z,b.w};
      #pragma unroll
      for (int kx=0;kx<5;++kx){
        float wv = wl[ky*5+kx];
        #pragma unroll
        for (int p=0;p<4;++p) acc[p] += wv * f[kx+p];
      }
    }
  }
  float bb = b2[oc];
  float4 st;
  st.x = fmaxf(acc[0]+bb, 0.f);
  st.y = fmaxf(acc[1]+bb, 0.f);
  st.z = fmaxf(acc[2]+bb, 0.f);
  st.w = fmaxf(acc[3]+bb, 0.f);
  *(float4*)&out[((n*64+oc)*128 + oy0+r)*128 + ox0 + c0] = st;
}

// ---------------- K3: LRN + 4-crop + 2x2 maxpool
__global__ __launch_bounds__(256) void k3_lrn_crop_pool(const float* __restrict__ h, float* __restrict__ out){
  int idx = blockIdx.x*256 + threadIdx.x;            // 2,032,128
  int j = idx % 63; int t1 = idx / 63;
  int i = t1 % 63; int t2 = t1 / 63;
  int c = t2 & 63; int b = t2 >> 6;
  int v = b >> 1, n = b & 1;
  int r0 = v & 1, c0 = v >> 1;
  const float* base  = h + ((n*64+c  )*128)*128;
  const float* basep = h + ((n*64+c-1)*128)*128;
  float m = -3.4e38f;
  #pragma unroll
  for (int a=0;a<2;++a)
    #pragma unroll
    for (int bb=0;bb<2;++bb){
      int y = r0+2*i+a, xx = c0+2*j+bb;
      float val = base[y*128+xx];
      float pv  = c ? basep[y*128+xx] : 0.f;
      m = fmaxf(m, lrn_one(val, pv));
    }
  out[idx] = m;
}

// ---------------- K4/K5 v2: conv 3x3, 64->64, SAME pad 1, relu. 1x4 px per thread.
// grid 2048 = [rowg 4][oc 64][b 8]; block tile 16 rows x 64 cols (63 used).
__global__ __launch_bounds__(256) void k_conv3x3(const float* __restrict__ in, const float* __restrict__ w,
                                                 const float* __restrict__ bias, float* __restrict__ out){
  __shared__ __align__(16) float t[1224];            // 18 rows x 68 (66 used)
  __shared__ float wl[9];
  int bid = blockIdx.x;
  int rowg = bid & 3; int t1 = bid >> 2;
  int oc = t1 & 63;   int b = t1 >> 6;
  int tid = threadIdx.x;
  int oy0 = rowg*16;
  int r = tid >> 4, c0 = (tid & 15)*4;
  float acc[4] = {0.f,0.f,0.f,0.f};
  for (int ic=0; ic<64; ++ic){
    __syncthreads();
    for (int u=tid; u<1224; u+=256){
      int rr = u/68, cc = u - rr*68;
      int gy = oy0+rr-1, gx = cc-1;
      t[u] = (cc<66 && (unsigned)gy<63u && (unsigned)gx<63u) ? in[((b*64+ic)*63+gy)*63+gx] : 0.f;
    }
    if (tid<9) wl[tid] = w[(oc*64+ic)*9+tid];
    __syncthreads();
    #pragma unroll
    for (int ky=0;ky<3;++ky){
      float4 a = *(const float4*)&t[(r+ky)*68 + c0];
      float4 b4 = *(const float4*)&t[(r+ky)*68 + c0 + 4];
      float f[8] = {a.x,a.y,a.z,a.w,b4.x,b4.y,b4.z,b4.w};
      #pragma unroll
      for (int kx=0;kx<3;++kx){
        float wv = wl[ky*3+kx];
        #pragma unroll
        for (int p=0;p<4;++p) acc[p] += wv * f[kx+p];
      }
    }
  }
  int oy = oy0 + r;
  if (oy < 63){
    float bb = bias[oc];
    #pragma unroll
    for (int p=0;p<4;++p){
      int ox = c0 + p;
      if (ox < 63)
        out[((b*64+oc)*63+oy)*63+ox] = fmaxf(acc[p]+bb, 0.f);
    }
  }
}

// ---------------- K6: LRN elementwise, f32 (8,64,63,63) -> bf16 padded (8,64,64,64)
__global__ __launch_bounds__(256) void k6_lrn_bf(const float* __restrict__ in, u16* __restrict__ outb){
  int idx = blockIdx.x*256+threadIdx.x;              // 2,097,152
  int col = idx & 63, iy = (idx>>6)&63, ic = (idx>>12)&63, b = idx>>18;
  u16 o = 0;
  if (col < 63 && iy < 63){
    int src = ((b*64+ic)*63 + iy)*63 + col;
    float v  = in[src];
    float pv = ic ? in[src - 3969] : 0.f;
    o = f2bf(lrn_one(v, pv));
  }
  outb[idx] = o;
}

// ---------------- K7m v3: conv 16x16 VALID via MFMA implicit GEMM, pipelined.
// in bf16 padded (8,64,64,64) -> y5 (8,1024,48,48) bf16
// grid 512 = [ocb 8 = bid&7][n8 8][r 8]; block 192 thr = 3 waves.
// LDS double-buffered itile[2]: [ic2(2)][win(7)][col(64)][j(8)]
__global__ __launch_bounds__(192, 2) void k7m(const u16* __restrict__ inb, const u16* __restrict__ wpk,
                                              const float* __restrict__ b5, u16* __restrict__ y5){
  __shared__ __align__(16) u16 itile[2][7168];       // 28,672 B
  int bid = blockIdx.x;
  int ocb = bid & 7;
  int rem = bid >> 3;
  int n8  = rem & 7;
  int r   = rem >> 3;                                // 0..7
  int tid = threadIdx.x;
  int w = tid / 64, lane = tid & 63, quad = lane >> 4, m = lane & 15;
  int ic2q = quad >> 1, kyh = quad & 1;

  f32x4 acc[8][6];
  #pragma unroll
  for (int tm=0;tm<8;++tm)
    #pragma unroll
    for (int t=0;t<6;++t) acc[tm][t] = (f32x4){0.f,0.f,0.f,0.f};

  const u16* gin    = inb + ((size_t)n8 * 64) * 4096;
  const u16* wblock = wpk + ((size_t)ocb << 21);

  // B-frag LDS element offsets for the 6 n-tiles (within one buffer)
  int boff[6];
  #pragma unroll
  for (int t=0;t<6;++t){
    int s = t/3;
    int win = 2*w + s + kyh;
    boff[t] = ((ic2q*7 + win)*64 + (t%3)*16 + m)*8;
  }

  // staging unit address precompute: unit v = tid + u*192, v < 1792
  int goff[10], lbase[10];
  #pragma unroll
  for (int u=0;u<10;++u){
    int v = tid + u*192;
    int vv = (v < 1792) ? v : 0;
    int cp = vv & 31, t2 = vv >> 5;                  // t2 < 56
    int iyp = t2 % 28, ic2 = t2 / 28;
    int iy0 = iyp*2;
    goff[u]  = ic2*4096 + iy0*64 + 2*cp + r*64;
    lbase[u] = ((ic2*7 + (iy0>>3))*64 + 2*cp)*8 + (iy0&7);
  }

  u32 s0[10], s1[10];
  auto stage_load = [&](int chunk){
    const u16* gq = gin + (size_t)(chunk*2)*4096;
    #pragma unroll
    for (int u=0;u<10;++u){
      int v = tid + u*192;
      if (v < 1792){
        const u16* g = gq + goff[u];
        s0[u] = *(const u32*)g;
        s1[u] = *(const u32*)(g + 64);
      }
    }
  };
  auto stage_write = [&](int buf){
    #pragma unroll
    for (int u=0;u<10;++u){
      int v = tid + u*192;
      if (v < 1792){
        u32 lo = (s0[u] & 0xffffu) | (s1[u] << 16);
        u32 hi = (s0[u] >> 16)     | (s1[u] & 0xffff0000u);
        *(u32*)&itile[buf][lbase[u]]     = lo;
        *(u32*)&itile[buf][lbase[u] + 8] = hi;
      }
    }
  };

  stage_load(0);
  stage_write(0);
  int buf = 0;

  #pragma unroll 1
  for (int chunk=0; chunk<32; ++chunk){
    __syncthreads();                                 // itile[buf] ready
    if (chunk < 31) stage_load(chunk+1);             // global prefetch (consumed after compute)
    const u16* wchunk = wblock + (chunk << 16);
    // preload kx=0 fragments
    short8 afn[8], bfn[6];
    {
      const u16* wk = wchunk + quad*1024 + m*8;
      #pragma unroll
      for (int tm=0;tm<8;++tm) afn[tm] = *(const short8*)(wk + tm*128);
      #pragma unroll
      for (int t=0;t<6;++t) bfn[t] = *(const short8*)&itile[buf][boff[t]];
    }
    #pragma unroll 1
    for (int kx=0; kx<16; ++kx){
      short8 afc[8], bfc[6];
      #pragma unroll
      for (int tm=0;tm<8;++tm) afc[tm] = afn[tm];
      #pragma unroll
      for (int t=0;t<6;++t) bfc[t] = bfn[t];
      int kxn = (kx+1) & 15;
      const u16* wkn = wchunk + kxn*4096 + quad*1024 + m*8;
      #pragma unroll
      for (int tm=0;tm<8;++tm) afn[tm] = *(const short8*)(wkn + tm*128);
      #pragma unroll
      for (int t=0;t<6;++t) bfn[t] = *(const short8*)&itile[buf][boff[t] + kxn*8];
      #pragma unroll
      for (int tm=0;tm<8;++tm)
        #pragma unroll
        for (int t=0;t<6;++t)
          acc[tm][t] = __builtin_amdgcn_mfma_f32_16x16x32_bf16(afc[tm], bfc[t], acc[tm][t], 0, 0, 0);
    }
    if (chunk < 31) stage_write(buf^1);
    buf ^= 1;
  }

  #pragma unroll
  for (int tm=0;tm<8;++tm){
    #pragma unroll
    for (int rr=0;rr<4;++rr){
      int oc = ocb*128 + tm*16 + quad*4 + rr;
      float bias = b5[oc];
      #pragma unroll
      for (int t=0;t<6;++t){
        int row = r + 16*w + 8*(t/3);
        int ox  = (t%3)*16 + m;
        float v = acc[tm][t][rr] + bias;
        v = v>0.f ? v : 0.f;
        y5[(((size_t)n8*1024 + oc)*48 + row)*48 + ox] = f2bf(v);
      }
    }
  }
}

// ---------------- K8a: 1x1 conv (1024->1024) MFMA + relu + w7-dot + block reduce + atomicAdd
__global__ __launch_bounds__(128) void k8a(const u16* __restrict__ y5, const u16* __restrict__ w6pk,
                                           const float* __restrict__ b6, const float* __restrict__ w7,
                                           float* __restrict__ accum){
  __shared__ __align__(16) u16 btile[96*136];        // 26,112 B
  __shared__ float red[8*96];
  int bid = blockIdx.x;
  int mb = bid & 7;
  int r  = bid >> 3;
  int n8 = r / 24, rp = r % 24;
  int r0 = 2*rp;
  int tid = threadIdx.x;
  int w = tid >> 6, lane = tid & 63, quad = lane >> 4, m = lane & 15;

  f32x4 acc[4][6];
  #pragma unroll
  for (int tm=0;tm<4;++tm)
    #pragma unroll
    for (int t=0;t<6;++t) acc[tm][t] = (f32x4){0.f,0.f,0.f,0.f};

  #pragma unroll 1
  for (int kc=0; kc<8; ++kc){
    __syncthreads();
    for (int u=tid; u<6144; u+=128){                 // 128 ic x 48 px-pairs
      int pp = u % 48; int ic2 = u / 48;
      int rowl = pp / 24; int ox0 = (pp % 24)*2;
      u32 val = *(const u32*)(y5 + (((size_t)(n8*1024 + kc*128 + ic2)*48) + r0 + rowl)*48 + ox0);
      int px = rowl*48 + ox0;
      btile[(px  )*136 + ic2] = (u16)(val & 0xffffu);
      btile[(px+1)*136 + ic2] = (u16)(val >> 16);
    }
    __syncthreads();
    #pragma unroll 1
    for (int kk=0; kk<4; ++kk){
      short8 af[4];
      #pragma unroll
      for (int tm=0;tm<4;++tm)
        af[tm] = *(const short8*)(w6pk + (size_t)(mb*128 + w*64 + tm*16 + m)*1024 + kc*128 + kk*32 + quad*8);
      short8 bf[6];
      #pragma unroll
      for (int t=0;t<6;++t){
        int pxl = ((t>=3)?48:0) + (t%3)*16 + m;
        bf[t] = *(const short8*)(btile + pxl*136 + kk*32 + quad*8);
      }
      #pragma unroll
      for (int tm=0;tm<4;++tm)
        #pragma unroll
        for (int t=0;t<6;++t)
          acc[tm][t] = __builtin_amdgcn_mfma_f32_16x16x32_bf16(af[tm], bf[t], acc[tm][t], 0, 0, 0);
    }
  }
  float part[6];
  #pragma unroll
  for (int t=0;t<6;++t) part[t]=0.f;
  #pragma unroll
  for (int tm=0;tm<4;++tm){
    #pragma unroll
    for (int rr=0;rr<4;++rr){
      int oc = mb*128 + w*64 + tm*16 + quad*4 + rr;
      float bb = b6[oc];
      float ww = w7[oc];
      #pragma unroll
      for (int t=0;t<6;++t){
        float z = acc[tm][t][rr] + bb;
        z = z>0.f ? z : 0.f;
        part[t] += ww*z;
      }
    }
  }
  #pragma unroll
  for (int t=0;t<6;++t){
    int pxl = ((t>=3)?48:0) + (t%3)*16 + m;
    red[(w*4+quad)*96 + pxl] = part[t];
  }
  __syncthreads();
  if (tid < 96){
    float s = 0.f;
    #pragma unroll
    for (int k=0;k<8;++k) s += red[k*96 + tid];
    int rowl = tid / 48, ox = tid % 48;
    atomicAdd(&accum[((size_t)n8*48 + r0 + rowl)*48 + ox], s);
  }
}

// ---------------- K8b: sigmoid + interweave. accum (8,48,48) -> out (2,1,96,96) f32
__global__ __launch_bounds__(256) void k8b(const float* __restrict__ accum, const float* __restrict__ b7,
                                           float* __restrict__ out){
  int idx = blockIdx.x*256 + threadIdx.x;
  if (idx >= 18432) return;
  int n8 = idx / 2304; int rem = idx % 2304;
  int oy = rem / 48, ox = rem % 48;
  float s = accum[idx] + b7[0];
  float sig = 1.f / (1.f + expf(-s));
  int v = n8 >> 1, n = n8 & 1;
  int a = v & 1, bcol = v >> 1;
  out[((size_t)n*96 + 2*oy + a)*96 + 2*ox + bcol] = sig;
}

// ---------------- workspace layout (fp32-element offsets)
// Cb   [0, 1,048,576)           bf16 padded (8,64,64,64) (k6 out, k7m in)
// A    [2,097,152, 4,194,304)   f32, dead after k5
// B    [4,194,304, 6,291,456)   f32, dead after k6
// F    [2,097,152, 11,534,336)  y5 bf16 (overlaps dead A,B; live k7m->k8a)
// Wpk5 [11,534,336, 19,922,944) bf16 16,777,216
// W6pk [19,922,944, 20,447,232) bf16 1,048,576
// accum[20,447,232, 20,465,664) f32 18,432

extern "C" void kernel_launch(void* const* d_in, const int* in_sizes, int n_in,
                              void* d_out, int out_size, void* d_ws, size_t ws_size,
                              hipStream_t stream){
  const float* x  = (const float*)d_in[0];
  const float* w1 = (const float*)d_in[1];
  const float* b1 = (const float*)d_in[2];
  const float* w2 = (const float*)d_in[3];
  const float* b2 = (const float*)d_in[4];
  const float* w3 = (const float*)d_in[5];
  const float* b3 = (const float*)d_in[6];
  const float* w4 = (const float*)d_in[7];
  const float* b4 = (const float*)d_in[8];
  const float* w5 = (const float*)d_in[9];
  const float* b5 = (const float*)d_in[10];
  const float* w6 = (const float*)d_in[11];
  const float* b6 = (const float*)d_in[12];
  const float* w7 = (const float*)d_in[13];
  const float* b7 = (const float*)d_in[14];
  float* ws = (float*)d_ws;
  float* C  = ws;                       // pooled f32 (k3 out, k4 in)
  u16*   Cb = (u16*)ws;                 // bf16 padded (k6 out, k7m in)
  float* A  = ws + 2097152;
  float* B  = ws + 4194304;
  u16*   F    = (u16*)(ws + 2097152);
  u16*   Wpk5 = (u16*)(ws + 11534336);
  u16*   W6pk = (u16*)(ws + 19922944);
  float* accum = ws + 20447232;
  float* out = (float*)d_out;

  hipLaunchKernelGGL(k0w5,            dim3(65536), dim3(256), 0, stream, w5, Wpk5);
  hipLaunchKernelGGL(k0w6,            dim3(4096),  dim3(256), 0, stream, w6, W6pk);
  hipLaunchKernelGGL(k0z,             dim3(72),    dim3(256), 0, stream, accum);
  hipLaunchKernelGGL(k1_conv7x7,      dim3(8192),  dim3(256), 0, stream, x, w1, b1, A);
  hipLaunchKernelGGL(k2_conv5x5,      dim3(2048),  dim3(256), 0, stream, A, w2, b2, B);
  hipLaunchKernelGGL(k3_lrn_crop_pool,dim3(7938),  dim3(256), 0, stream, B, C);
  hipLaunchKernelGGL(k_conv3x3,       dim3(2048),  dim3(256), 0, stream, C, w3, b3, A);
  hipLaunchKernelGGL(k_conv3x3,       dim3(2048),  dim3(256), 0, stream, A, w4, b4, B);
  hipLaunchKernelGGL(k6_lrn_bf,       dim3(8192),  dim3(256), 0, stream, B, Cb);
  hipLaunchKernelGGL(k7m,             dim3(512),   dim3(192), 0, stream, Cb, Wpk5, b5, F);
  hipLaunchKernelGGL(k8a,             dim3(1536),  dim3(128), 0, stream, F, W6pk, b6, w7, accum);
  hipLaunchKernelGGL(k8b,             dim3(72),    dim3(256), 0, stream, accum, b7, out);
}

// Round 7
// 1983.869 us; speedup vs baseline: 1.2094x; 1.2094x over previous
//
#include <hip/hip_runtime.h>

typedef unsigned short u16;
typedef unsigned int   u32;
typedef unsigned long long u64;
typedef short short8 __attribute__((ext_vector_type(8)));
typedef float f32x4  __attribute__((ext_vector_type(4)));

__device__ __forceinline__ u16 f2bf(float f){
  u32 u = __float_as_uint(f);
  u32 r = (u + 0x7fffu + ((u >> 16) & 1u)) >> 16;
  return (u16)r;
}
__device__ __forceinline__ float lrn_one(float v, float pv){
  float avg = 0.5f*(v*v + pv*pv);
  float d = 1.0f + 2e-5f*avg;
  return v * exp2f(-0.75f * log2f(d));   // d >= 1, safe
}

// ---------------- K0a: prepack w5 fp32 [1024][64][16][16] -> bf16 fragment order
// Wpk5[ocb(8)][chunk(32)][kx(16)][quad(4)][oc128(128)][j(8)]
__global__ __launch_bounds__(256) void k0w5(const float* __restrict__ w5, u16* __restrict__ wpk){
  int idx = blockIdx.x*256 + threadIdx.x;            // 16,777,216
  int j     =  idx        & 7;
  int oc128 = (idx >> 3)  & 127;
  int quad  = (idx >> 10) & 3;
  int kx    = (idx >> 12) & 15;
  int chunk = (idx >> 16) & 31;
  int ocb   =  idx >> 21;
  int oc = ocb*128 + oc128;
  int ic = chunk*2 + (quad>>1);
  int ky = (quad&1)*8 + j;
  wpk[idx] = f2bf(w5[((oc*64 + ic)*16 + ky)*16 + kx]);
}

// ---------------- K0b: prepack w6 fp32[1024][1024] -> bf16
__global__ __launch_bounds__(256) void k0w6(const float* __restrict__ w6, u16* __restrict__ wpk){
  int idx = blockIdx.x*256 + threadIdx.x;            // 1,048,576
  wpk[idx] = f2bf(w6[idx]);
}

// ---------------- K0c: zero the k8 accumulation buffer (18432 f32)
__global__ __launch_bounds__(256) void k0z(float* __restrict__ accum){
  int idx = blockIdx.x*256 + threadIdx.x;
  if (idx < 18432) accum[idx] = 0.f;
}

// ---------------- K0d: zero the k7 partial buffer (18,874,368 f32), float4 stores
__global__ __launch_bounds__(256) void k0zbig(float* __restrict__ p){
  int i = blockIdx.x*256 + threadIdx.x;              // 4,718,592
  ((float4*)p)[i] = make_float4(0.f,0.f,0.f,0.f);
}

// ---------------- K1: conv 7x7, 1->64, SAME pad 3, relu
__global__ __launch_bounds__(256) void k1_conv7x7(const float* __restrict__ x, const float* __restrict__ w1,
                                                  const float* __restrict__ b1, float* __restrict__ out){
  int idx = blockIdx.x*256 + threadIdx.x;            // 2,097,152
  int ox = idx & 127, oy = (idx>>7)&127, oc = (idx>>14)&63, n = idx>>20;
  float acc = b1[oc];
  const float* wb = w1 + oc*49;
  const float* xb = x + n*16384;
  #pragma unroll
  for (int ky=0;ky<7;++ky){
    int y = oy + ky - 3;
    if ((unsigned)y < 128u){
      #pragma unroll
      for (int kx=0;kx<7;++kx){
        int xx = ox + kx - 3;
        if ((unsigned)xx < 128u)
          acc += wb[ky*7+kx] * xb[y*128+xx];
      }
    }
  }
  out[idx] = acc > 0.f ? acc : 0.f;
}

// ---------------- K2 v2: conv 5x5, 64->64, SAME pad 2, relu. 1x4 px per thread.
__global__ __launch_bounds__(256) void k2_conv5x5(const float* __restrict__ in, const float* __restrict__ w2,
                                                  const float* __restrict__ b2, float* __restrict__ out){
  __shared__ __align__(16) float t[1360];            // 20 rows x 68 cols
  __shared__ float wl[25];
  int bid = blockIdx.x;
  int colg = bid & 1; int t1 = bid >> 1;
  int rowg = t1 & 7;  int t2 = t1 >> 3;
  int oc = t2 & 63;   int n = t2 >> 6;
  int tid = threadIdx.x;
  int oy0 = rowg*16, ox0 = colg*64;
  int r = tid >> 4, c0 = (tid & 15)*4;
  float acc[4] = {0.f,0.f,0.f,0.f};
  for (int ic=0; ic<64; ++ic){
    __syncthreads();
    for (int u=tid; u<1360; u+=256){
      int rr = u/68, cc = u - rr*68;
      int gy = oy0+rr-2, gx = ox0+cc-2;
      t[u] = ((unsigned)gy<128u && (unsigned)gx<128u) ? in[((n*64+ic)*128+gy)*128+gx] : 0.f;
    }
    if (tid < 25) wl[tid] = w2[(oc*64+ic)*25 + tid];
    __syncthreads();
    #pragma unroll
    for (int ky=0;ky<5;++ky){
      float4 a = *(const float4*)&t[(r+ky)*68 + c0];
      float4 b = *(const float4*)&t[(r+ky)*68 + c0 + 4];
      float f[8] = {a.x,a.y,a.z,a.w,b.x,b.y,b.z,b.w};
      #pragma unroll
      for (int kx=0;kx<5;++kx){
        float wv = wl[ky*5+kx];
        #pragma unroll
        for (int p=0;p<4;++p) acc[p] += wv * f[kx+p];
      }
    }
  }
  float bb = b2[oc];
  float4 st;
  st.x = fmaxf(acc[0]+bb, 0.f);
  st.y = fmaxf(acc[1]+bb, 0.f);
  st.z = fmaxf(acc[2]+bb, 0.f);
  st.w = fmaxf(acc[3]+bb, 0.f);
  *(float4*)&out[((n*64+oc)*128 + oy0+r)*128 + ox0 + c0] = st;
}

// ---------------- K3: LRN + 4-crop + 2x2 maxpool
__global__ __launch_bounds__(256) void k3_lrn_crop_pool(const float* __restrict__ h, float* __restrict__ out){
  int idx = blockIdx.x*256 + threadIdx.x;            // 2,032,128
  int j = idx % 63; int t1 = idx / 63;
  int i = t1 % 63; int t2 = t1 / 63;
  int c = t2 & 63; int b = t2 >> 6;
  int v = b >> 1, n = b & 1;
  int r0 = v & 1, c0 = v >> 1;
  const float* base  = h + ((n*64+c  )*128)*128;
  const float* basep = h + ((n*64+c-1)*128)*128;
  float m = -3.4e38f;
  #pragma unroll
  for (int a=0;a<2;++a)
    #pragma unroll
    for (int bb=0;bb<2;++bb){
      int y = r0+2*i+a, xx = c0+2*j+bb;
      float val = base[y*128+xx];
      float pv  = c ? basep[y*128+xx] : 0.f;
      m = fmaxf(m, lrn_one(val, pv));
    }
  out[idx] = m;
}

// ---------------- K4/K5 v2: conv 3x3, 64->64, SAME pad 1, relu. 1x4 px per thread.
__global__ __launch_bounds__(256) void k_conv3x3(const float* __restrict__ in, const float* __restrict__ w,
                                                 const float* __restrict__ bias, float* __restrict__ out){
  __shared__ __align__(16) float t[1224];            // 18 rows x 68 (66 used)
  __shared__ float wl[9];
  int bid = blockIdx.x;
  int rowg = bid & 3; int t1 = bid >> 2;
  int oc = t1 & 63;   int b = t1 >> 6;
  int tid = threadIdx.x;
  int oy0 = rowg*16;
  int r = tid >> 4, c0 = (tid & 15)*4;
  float acc[4] = {0.f,0.f,0.f,0.f};
  for (int ic=0; ic<64; ++ic){
    __syncthreads();
    for (int u=tid; u<1224; u+=256){
      int rr = u/68, cc = u - rr*68;
      int gy = oy0+rr-1, gx = cc-1;
      t[u] = (cc<66 && (unsigned)gy<63u && (unsigned)gx<63u) ? in[((b*64+ic)*63+gy)*63+gx] : 0.f;
    }
    if (tid<9) wl[tid] = w[(oc*64+ic)*9+tid];
    __syncthreads();
    #pragma unroll
    for (int ky=0;ky<3;++ky){
      float4 a = *(const float4*)&t[(r+ky)*68 + c0];
      float4 b4 = *(const float4*)&t[(r+ky)*68 + c0 + 4];
      float f[8] = {a.x,a.y,a.z,a.w,b4.x,b4.y,b4.z,b4.w};
      #pragma unroll
      for (int kx=0;kx<3;++kx){
        float wv = wl[ky*3+kx];
        #pragma unroll
        for (int p=0;p<4;++p) acc[p] += wv * f[kx+p];
      }
    }
  }
  int oy = oy0 + r;
  if (oy < 63){
    float bb = bias[oc];
    #pragma unroll
    for (int p=0;p<4;++p){
      int ox = c0 + p;
      if (ox < 63)
        out[((b*64+oc)*63+oy)*63+ox] = fmaxf(acc[p]+bb, 0.f);
    }
  }
}

// ---------------- K6: LRN elementwise, f32 (8,64,63,63) -> bf16 padded (8,64,64,64)
__global__ __launch_bounds__(256) void k6_lrn_bf(const float* __restrict__ in, u16* __restrict__ outb){
  int idx = blockIdx.x*256+threadIdx.x;              // 2,097,152
  int col = idx & 63, iy = (idx>>6)&63, ic = (idx>>12)&63, b = idx>>18;
  u16 o = 0;
  if (col < 63 && iy < 63){
    int src = ((b*64+ic)*63 + iy)*63 + col;
    float v  = in[src];
    float pv = ic ? in[src - 3969] : 0.f;
    o = f2bf(lrn_one(v, pv));
  }
  outb[idx] = o;
}

// ---------------- K7m v4: conv 16x16 VALID via MFMA implicit GEMM (round-5 v2 loop).
// ksplit=1, mode=0: grid 512, full K, writes y5 (bias+relu+f2bf).  [verified 720us path]
// ksplit=2, mode=1: grid 1024, half K per block, fp32 atomicAdd partials into part.
__global__ __launch_bounds__(192, 2) void k7m(const u16* __restrict__ inb, const u16* __restrict__ wpk,
                                              const float* __restrict__ b5, u16* __restrict__ y5,
                                              float* __restrict__ part, int ksplit, int mode){
  __shared__ __align__(16) u16 itile[7168];          // 14,336 B
  int bid = blockIdx.x;
  int ocb = bid & 7;
  int rem = bid >> 3;
  int n8  = rem & 7;
  int r   = (rem >> 3) & 7;
  int ks  = rem >> 6;                                // 0 when grid 512
  int nch = 32 / ksplit;
  int c0 = ks * nch, c1 = c0 + nch;
  int tid = threadIdx.x;
  int w = tid / 64, lane = tid & 63, quad = lane >> 4, m = lane & 15;
  int ic2q = quad >> 1, kyh = quad & 1;

  f32x4 acc[8][6];
  #pragma unroll
  for (int tm=0;tm<8;++tm)
    #pragma unroll
    for (int t=0;t<6;++t) acc[tm][t] = (f32x4){0.f,0.f,0.f,0.f};

  const u16* gin    = inb + ((size_t)n8 * 64) * 4096;
  const u16* wblock = wpk + ((size_t)ocb << 21);

  int boff[6];
  #pragma unroll
  for (int t=0;t<6;++t){
    int s = t/3;
    int win = 2*w + s + kyh;
    boff[t] = ((ic2q*7 + win)*64 + (t%3)*16 + m)*8;
  }

  #pragma unroll 1
  for (int chunk=c0; chunk<c1; ++chunk){
    __syncthreads();
    // stage 2 ic x 56 rows x 64 cols, transposed into [ic2][win][col][j]
    {
      const u16* gq = gin + (size_t)(chunk*2)*4096 + r*64;
      for (int v = tid; v < 1792; v += 192){           // 2 ic x 28 iy-pairs x 32 col-pairs
        int cp  = v & 31;
        int t2  = v >> 5;                              // 0..55
        int iyp = t2 % 28;
        int ic2 = t2 / 28;
        int iy0 = iyp*2;
        const u16* g = gq + ic2*4096 + iy0*64 + 2*cp;
        u32 d0 = *(const u32*)(g);
        u32 d1 = *(const u32*)(g + 64);
        u32 lo = (d0 & 0xffffu) | (d1 << 16);          // col 2cp:   rows iy0, iy0+1
        u32 hi = (d0 >> 16) | (d1 & 0xffff0000u);      // col 2cp+1
        int win = iy0 >> 3, j = iy0 & 7;
        int base = ((ic2*7 + win)*64 + 2*cp)*8 + j;
        *(u32*)&itile[base]     = lo;
        *(u32*)&itile[base + 8] = hi;
      }
    }
    __syncthreads();
    const u16* wchunk = wblock + (chunk << 16);
    #pragma unroll 1
    for (int kx=0; kx<16; ++kx){
      short8 bf[6];
      #pragma unroll
      for (int t=0;t<6;++t)
        bf[t] = *(const short8*)&itile[boff[t] + kx*8];
      const u16* wk = wchunk + kx*4096 + quad*1024 + m*8;
      #pragma unroll
      for (int tg=0; tg<2; ++tg){
        short8 af[4];
        #pragma unroll
        for (int q2=0;q2<4;++q2)
          af[q2] = *(const short8*)(wk + (tg*4+q2)*128);
        #pragma unroll
        for (int q2=0;q2<4;++q2)
          #pragma unroll
          for (int t=0;t<6;++t)
            acc[tg*4+q2][t] = __builtin_amdgcn_mfma_f32_16x16x32_bf16(af[q2], bf[t], acc[tg*4+q2][t], 0, 0, 0);
      }
    }
  }
  if (mode == 0){
    #pragma unroll
    for (int tm=0;tm<8;++tm){
      #pragma unroll
      for (int rr=0;rr<4;++rr){
        int oc = ocb*128 + tm*16 + quad*4 + rr;
        float bias = b5[oc];
        #pragma unroll
        for (int t=0;t<6;++t){
          int row = r + 16*w + 8*(t/3);
          int ox  = (t%3)*16 + m;
          float v = acc[tm][t][rr] + bias;
          v = v>0.f ? v : 0.f;
          y5[(((size_t)n8*1024 + oc)*48 + row)*48 + ox] = f2bf(v);
        }
      }
    }
  } else {
    #pragma unroll
    for (int tm=0;tm<8;++tm){
      #pragma unroll
      for (int rr=0;rr<4;++rr){
        int oc = ocb*128 + tm*16 + quad*4 + rr;
        #pragma unroll
        for (int t=0;t<6;++t){
          int row = r + 16*w + 8*(t/3);
          int ox  = (t%3)*16 + m;
          atomicAdd(&part[(((size_t)n8*1024 + oc)*48 + row)*48 + ox], acc[tm][t][rr]);
        }
      }
    }
  }
}

// ---------------- K7r: part (f32) + bias -> relu -> bf16 y5. 4 elems/thread.
__global__ __launch_bounds__(256) void k7r(const float* __restrict__ part, const float* __restrict__ b5,
                                           u16* __restrict__ y5){
  int i = blockIdx.x*256 + threadIdx.x;              // 4,718,592
  int e0 = i*4;
  int oc = (e0 / 2304) & 1023;
  float bb = b5[oc];
  float4 v = ((const float4*)part)[i];
  u64 pk = (u64)f2bf(fmaxf(v.x+bb,0.f))
         | ((u64)f2bf(fmaxf(v.y+bb,0.f)) << 16)
         | ((u64)f2bf(fmaxf(v.z+bb,0.f)) << 32)
         | ((u64)f2bf(fmaxf(v.w+bb,0.f)) << 48);
  *(u64*)&y5[e0] = pk;
}

// ---------------- K8a: 1x1 conv (1024->1024) MFMA + relu + w7-dot + block reduce + atomicAdd
__global__ __launch_bounds__(128) void k8a(const u16* __restrict__ y5, const u16* __restrict__ w6pk,
                                           const float* __restrict__ b6, const float* __restrict__ w7,
                                           float* __restrict__ accum){
  __shared__ __align__(16) u16 btile[96*136];        // 26,112 B
  __shared__ float red[8*96];
  int bid = blockIdx.x;
  int mb = bid & 7;
  int r  = bid >> 3;
  int n8 = r / 24, rp = r % 24;
  int r0 = 2*rp;
  int tid = threadIdx.x;
  int w = tid >> 6, lane = tid & 63, quad = lane >> 4, m = lane & 15;

  f32x4 acc[4][6];
  #pragma unroll
  for (int tm=0;tm<4;++tm)
    #pragma unroll
    for (int t=0;t<6;++t) acc[tm][t] = (f32x4){0.f,0.f,0.f,0.f};

  #pragma unroll 1
  for (int kc=0; kc<8; ++kc){
    __syncthreads();
    for (int u=tid; u<6144; u+=128){                 // 128 ic x 48 px-pairs
      int pp = u % 48; int ic2 = u / 48;
      int rowl = pp / 24; int ox0 = (pp % 24)*2;
      u32 val = *(const u32*)(y5 + (((size_t)(n8*1024 + kc*128 + ic2)*48) + r0 + rowl)*48 + ox0);
      int px = rowl*48 + ox0;
      btile[(px  )*136 + ic2] = (u16)(val & 0xffffu);
      btile[(px+1)*136 + ic2] = (u16)(val >> 16);
    }
    __syncthreads();
    #pragma unroll 1
    for (int kk=0; kk<4; ++kk){
      short8 af[4];
      #pragma unroll
      for (int tm=0;tm<4;++tm)
        af[tm] = *(const short8*)(w6pk + (size_t)(mb*128 + w*64 + tm*16 + m)*1024 + kc*128 + kk*32 + quad*8);
      short8 bf[6];
      #pragma unroll
      for (int t=0;t<6;++t){
        int pxl = ((t>=3)?48:0) + (t%3)*16 + m;
        bf[t] = *(const short8*)(btile + pxl*136 + kk*32 + quad*8);
      }
      #pragma unroll
      for (int tm=0;tm<4;++tm)
        #pragma unroll
        for (int t=0;t<6;++t)
          acc[tm][t] = __builtin_amdgcn_mfma_f32_16x16x32_bf16(af[tm], bf[t], acc[tm][t], 0, 0, 0);
    }
  }
  float part[6];
  #pragma unroll
  for (int t=0;t<6;++t) part[t]=0.f;
  #pragma unroll
  for (int tm=0;tm<4;++tm){
    #pragma unroll
    for (int rr=0;rr<4;++rr){
      int oc = mb*128 + w*64 + tm*16 + quad*4 + rr;
      float bb = b6[oc];
      float ww = w7[oc];
      #pragma unroll
      for (int t=0;t<6;++t){
        float z = acc[tm][t][rr] + bb;
        z = z>0.f ? z : 0.f;
        part[t] += ww*z;
      }
    }
  }
  #pragma unroll
  for (int t=0;t<6;++t){
    int pxl = ((t>=3)?48:0) + (t%3)*16 + m;
    red[(w*4+quad)*96 + pxl] = part[t];
  }
  __syncthreads();
  if (tid < 96){
    float s = 0.f;
    #pragma unroll
    for (int k=0;k<8;++k) s += red[k*96 + tid];
    int rowl = tid / 48, ox = tid % 48;
    atomicAdd(&accum[((size_t)n8*48 + r0 + rowl)*48 + ox], s);
  }
}

// ---------------- K8b: sigmoid + interweave. accum (8,48,48) -> out (2,1,96,96) f32
__global__ __launch_bounds__(256) void k8b(const float* __restrict__ accum, const float* __restrict__ b7,
                                           float* __restrict__ out){
  int idx = blockIdx.x*256 + threadIdx.x;
  if (idx >= 18432) return;
  int n8 = idx / 2304; int rem = idx % 2304;
  int oy = rem / 48, ox = rem % 48;
  float s = accum[idx] + b7[0];
  float sig = 1.f / (1.f + expf(-s));
  int v = n8 >> 1, n = n8 & 1;
  int a = v & 1, bcol = v >> 1;
  out[((size_t)n*96 + 2*oy + a)*96 + 2*ox + bcol] = sig;
}

extern "C" void kernel_launch(void* const* d_in, const int* in_sizes, int n_in,
                              void* d_out, int out_size, void* d_ws, size_t ws_size,
                              hipStream_t stream){
  const float* x  = (const float*)d_in[0];
  const float* w1 = (const float*)d_in[1];
  const float* b1 = (const float*)d_in[2];
  const float* w2 = (const float*)d_in[3];
  const float* b2 = (const float*)d_in[4];
  const float* w3 = (const float*)d_in[5];
  const float* b3 = (const float*)d_in[6];
  const float* w4 = (const float*)d_in[7];
  const float* b4 = (const float*)d_in[8];
  const float* w5 = (const float*)d_in[9];
  const float* b5 = (const float*)d_in[10];
  const float* w6 = (const float*)d_in[11];
  const float* b6 = (const float*)d_in[12];
  const float* w7 = (const float*)d_in[13];
  const float* b7 = (const float*)d_in[14];
  float* ws = (float*)d_ws;
  float* out = (float*)d_out;

  const size_t NEED_BIG = 39340160ull * 4ull;        // 157.4 MB
  bool big = (ws_size >= NEED_BIG);

  if (big){
    // big layout (f32-element offsets):
    // C  [0, 2,097,152) ; A [2,097,152, 4,194,304) ; B [4,194,304, 6,291,456)
    // Cb (u16) over C's first half; part [2,097,152, 20,971,520) overlaps dead A,B
    // y5 [20,971,520, 30,408,704) ; Wpk5 [30,408,704, 38,797,312)
    // W6pk [38,797,312, 39,321,728) ; accum8 [39,321,728, 39,340,160)
    float* C  = ws;
    u16*   Cb = (u16*)ws;
    float* A  = ws + 2097152;
    float* B  = ws + 4194304;
    float* part = ws + 2097152;
    u16*   F    = (u16*)(ws + 20971520);
    u16*   Wpk5 = (u16*)(ws + 30408704);
    u16*   W6pk = (u16*)(ws + 38797312);
    float* accum = ws + 39321728;

    hipLaunchKernelGGL(k0w5,            dim3(65536), dim3(256), 0, stream, w5, Wpk5);
    hipLaunchKernelGGL(k0w6,            dim3(4096),  dim3(256), 0, stream, w6, W6pk);
    hipLaunchKernelGGL(k0z,             dim3(72),    dim3(256), 0, stream, accum);
    hipLaunchKernelGGL(k1_conv7x7,      dim3(8192),  dim3(256), 0, stream, x, w1, b1, A);
    hipLaunchKernelGGL(k2_conv5x5,      dim3(2048),  dim3(256), 0, stream, A, w2, b2, B);
    hipLaunchKernelGGL(k3_lrn_crop_pool,dim3(7938),  dim3(256), 0, stream, B, C);
    hipLaunchKernelGGL(k_conv3x3,       dim3(2048),  dim3(256), 0, stream, C, w3, b3, A);
    hipLaunchKernelGGL(k_conv3x3,       dim3(2048),  dim3(256), 0, stream, A, w4, b4, B);
    hipLaunchKernelGGL(k6_lrn_bf,       dim3(8192),  dim3(256), 0, stream, B, Cb);
    hipLaunchKernelGGL(k0zbig,          dim3(18432), dim3(256), 0, stream, part);
    hipLaunchKernelGGL(k7m,             dim3(1024),  dim3(192), 0, stream, Cb, Wpk5, b5, F, part, 2, 1);
    hipLaunchKernelGGL(k7r,             dim3(18432), dim3(256), 0, stream, part, b5, F);
    hipLaunchKernelGGL(k8a,             dim3(1536),  dim3(128), 0, stream, F, W6pk, b6, w7, accum);
    hipLaunchKernelGGL(k8b,             dim3(72),    dim3(256), 0, stream, accum, b7, out);
  } else {
    // small layout (round-5/6 verified, <= 82 MB)
    float* C  = ws;
    u16*   Cb = (u16*)ws;
    float* A  = ws + 2097152;
    float* B  = ws + 4194304;
    u16*   F    = (u16*)(ws + 2097152);
    u16*   Wpk5 = (u16*)(ws + 11534336);
    u16*   W6pk = (u16*)(ws + 19922944);
    float* accum = ws + 20447232;

    hipLaunchKernelGGL(k0w5,            dim3(65536), dim3(256), 0, stream, w5, Wpk5);
    hipLaunchKernelGGL(k0w6,            dim3(4096),  dim3(256), 0, stream, w6, W6pk);
    hipLaunchKernelGGL(k0z,             dim3(72),    dim3(256), 0, stream, accum);
    hipLaunchKernelGGL(k1_conv7x7,      dim3(8192),  dim3(256), 0, stream, x, w1, b1, A);
    hipLaunchKernelGGL(k2_conv5x5,      dim3(2048),  dim3(256), 0, stream, A, w2, b2, B);
    hipLaunchKernelGGL(k3_lrn_crop_pool,dim3(7938),  dim3(256), 0, stream, B, C);
    hipLaunchKernelGGL(k_conv3x3,       dim3(2048),  dim3(256), 0, stream, C, w3, b3, A);
    hipLaunchKernelGGL(k_conv3x3,       dim3(2048),  dim3(256), 0, stream, A, w4, b4, B);
    hipLaunchKernelGGL(k6_lrn_bf,       dim3(8192),  dim3(256), 0, stream, B, Cb);
    hipLaunchKernelGGL(k7m,             dim3(512),   dim3(192), 0, stream, Cb, Wpk5, b5, F, ws, 1, 0);
    hipLaunchKernelGGL(k8a,             dim3(1536),  dim3(128), 0, stream, F, W6pk, b6, w7, accum);
    hipLaunchKernelGGL(k8b,             dim3(72),    dim3(256), 0, stream, accum, b7, out);
  }
}